// Round 4
// baseline (2290.282 us; speedup 1.0000x reference)
//
#include <hip/hip_runtime.h>
#include <hip/hip_bf16.h>
#include <math.h>

#define L_SEQ 64
#define NB    128
#define EMBD  512
#define HID   256
#define G4    1024      // 4*HID
#define NCOL  2048      // 2 dirs * 4H
#define DDIM  512       // 2*HID
#define MS    (L_SEQ*NB)   // 8192 rows per sentence
#define MTOT  (2*MS)       // 16384 combined rows

typedef __bf16 bf16_t;
typedef bf16_t bf16x8 __attribute__((ext_vector_type(8)));
typedef float  floatx4 __attribute__((ext_vector_type(4)));
typedef float  floatx8 __attribute__((ext_vector_type(8)));

__device__ __forceinline__ bf16x8 cvt_bf16x8(floatx8 v) {
    bf16x8 r;
    r[0]=(bf16_t)v[0]; r[1]=(bf16_t)v[1]; r[2]=(bf16_t)v[2]; r[3]=(bf16_t)v[3];
    r[4]=(bf16_t)v[4]; r[5]=(bf16_t)v[5]; r[6]=(bf16_t)v[6]; r[7]=(bf16_t)v[7];
    return r;
}

__device__ __forceinline__ void gload_lds16(const bf16_t* g, bf16_t* l) {
    __builtin_amdgcn_global_load_lds(
        (const __attribute__((address_space(1))) unsigned int*)(g),
        (__attribute__((address_space(3))) unsigned int*)(l), 16, 0, 0);
}

__device__ __forceinline__ float fsigmoid(float x) {
    return __builtin_amdgcn_rcpf(1.0f + __expf(-x));
}
__device__ __forceinline__ float ftanh(float x) {
    return 1.0f - 2.0f * __builtin_amdgcn_rcpf(__expf(2.0f*x) + 1.0f);
}

// ---------------------------------------------------------------------------
// Pack kernels (unchanged)
// ---------------------------------------------------------------------------
__global__ __launch_bounds__(256) void k_pack_a(const int* __restrict__ t1,
                                                const int* __restrict__ t2,
                                                const float* __restrict__ emb,
                                                bf16_t* __restrict__ A)
{
    int gid = blockIdx.x*256 + threadIdx.x;
    int row = gid >> 6;
    int k8  = (gid & 63) * 8;
    int tok = (row < MS) ? t1[row] : t2[row - MS];
    floatx8 v = *(const floatx8*)(emb + (size_t)tok*EMBD + k8);
    *(bf16x8*)(A + (size_t)row*EMBD + k8) = cvt_bf16x8(v);
}

__global__ __launch_bounds__(256) void k_pack_b(const float* __restrict__ wih_f,
                                                const float* __restrict__ wih_b,
                                                bf16_t* __restrict__ B)
{
    int gid = blockIdx.x*256 + threadIdx.x;
    int n   = gid >> 6;
    int k8  = (gid & 63) * 8;
    const float* src = (n >= 1024) ? (wih_b + (size_t)(n-1024)*EMBD)
                                   : (wih_f + (size_t)n*EMBD);
    *(bf16x8*)(B + (size_t)n*EMBD + k8) = cvt_bf16x8(*(const floatx8*)(src + k8));
}

__global__ __launch_bounds__(256) void k_pack_whh(const float* __restrict__ whh_f,
                                                  const float* __restrict__ whh_b,
                                                  bf16_t* __restrict__ whhB)
{
    int gid = blockIdx.x*256 + threadIdx.x;
    int r2  = gid >> 5;
    int k8  = (gid & 31) * 8;
    const float* src = (r2 >= 1024) ? (whh_b + (size_t)(r2-1024)*HID)
                                    : (whh_f + (size_t)r2*HID);
    *(bf16x8*)(whhB + (size_t)r2*HID + k8) = cvt_bf16x8(*(const floatx8*)(src + k8));
}

__global__ __launch_bounds__(256) void k_pack_bias(const float* __restrict__ bih_f,
                                                   const float* __restrict__ bhh_f,
                                                   const float* __restrict__ bih_b,
                                                   const float* __restrict__ bhh_b,
                                                   float* __restrict__ bias)
{
    int n = blockIdx.x*256 + threadIdx.x;
    bias[n] = (n >= 1024) ? (bih_b[n-1024] + bhh_b[n-1024])
                          : (bih_f[n] + bhh_f[n]);
}

// ---------------------------------------------------------------------------
// xg GEMM (m97-style, unchanged)
// ---------------------------------------------------------------------------
__global__ __launch_bounds__(256) void xg_gemm2(const bf16_t* __restrict__ A,
                                                const bf16_t* __restrict__ B,
                                                const float* __restrict__ bias,
                                                float* __restrict__ xg)
{
    __shared__ bf16_t As[128*32];
    __shared__ bf16_t Bs[128*32];
    const int tid  = threadIdx.x;
    const int wid  = tid >> 6;
    const int lane = tid & 63;
    const int l15  = lane & 15;
    const int quad = lane >> 4;
    const int m0   = blockIdx.y * 128;
    const int n0   = blockIdx.x * 128;
    const int mw   = (wid & 1) * 64;
    const int nw   = (wid >> 1) * 64;

    float biasv[4];
#pragma unroll
    for (int ni = 0; ni < 4; ++ni) biasv[ni] = bias[n0 + nw + ni*16 + l15];

    const int srow = tid >> 2;
    const int sk8  = (tid & 3) * 8;

    floatx4 acc[4][4] = {};
    for (int kk = 0; kk < EMBD; kk += 32) {
#pragma unroll
        for (int inst = 0; inst < 2; ++inst) {
            gload_lds16(A + (size_t)(m0 + inst*64 + srow)*EMBD + kk + sk8,
                        As + inst*2048 + wid*512);
            gload_lds16(B + (size_t)(n0 + inst*64 + srow)*EMBD + kk + sk8,
                        Bs + inst*2048 + wid*512);
        }
        __syncthreads();
        bf16x8 a[4], b[4];
#pragma unroll
        for (int mi = 0; mi < 4; ++mi)
            a[mi] = *(const bf16x8*)(As + (mw + mi*16 + l15)*32 + quad*8);
#pragma unroll
        for (int ni = 0; ni < 4; ++ni)
            b[ni] = *(const bf16x8*)(Bs + (nw + ni*16 + l15)*32 + quad*8);
#pragma unroll
        for (int mi = 0; mi < 4; ++mi)
#pragma unroll
            for (int ni = 0; ni < 4; ++ni)
                acc[mi][ni] = __builtin_amdgcn_mfma_f32_16x16x32_bf16(
                                  a[mi], b[ni], acc[mi][ni], 0, 0, 0);
        __syncthreads();
    }
#pragma unroll
    for (int mi = 0; mi < 4; ++mi)
#pragma unroll
        for (int ni = 0; ni < 4; ++ni)
#pragma unroll
            for (int r = 0; r < 4; ++r) {
                int m = m0 + mw + mi*16 + quad*4 + r;
                int n = n0 + nw + ni*16 + l15;
                xg[(size_t)m*NCOL + n] = acc[mi][ni][r] + biasv[ni];
            }
}

// ---------------------------------------------------------------------------
// LSTM scan v4: 512 single-wave blocks. Wave = (stream s2, chunk, wv):
// owns batch rows [chunk*16,+16) and hidden units [wv*16,+16) of dir dr.
// Its Whh slice (4 gates x 16 units x 256 k, bf16) lives ENTIRELY in VGPRs
// (32 frags = 128 regs) -> zero per-step weight traffic. Per step:
//   spin on 16 peer flags -> fence -> read full h_t (8 KB, A-frag layout,
//   coalesced) from global hx -> 32 MFMAs -> epilogue -> write o + h-slice
//   -> fence -> publish flag.
// h_t lives in hx frame t&1 (ping-pong). t=0: h_0=0, skip wait+MFMA.
// ---------------------------------------------------------------------------
__global__ __launch_bounds__(64, 1) void lstm_scan4(
    const bf16_t* __restrict__ whhB,   // [2][1024][256] bf16
    const float*  __restrict__ xg,     // [2*8192][2048] fp32
    float* __restrict__ o1, float* __restrict__ o2,
    bf16_t* __restrict__ hx,           // [32 groups][2 frames][4096 bf16]
    int* __restrict__ flags)           // [32 groups][16 waves]
{
    const int gid  = blockIdx.x;          // 0..511
    const int lane = threadIdx.x;         // 0..63
    const int l15  = lane & 15;
    const int quad = lane >> 4;
    const int s2   = gid >> 7;            // stream = sent*2 + dr
    const int sent = s2 >> 1;
    const int dr   = s2 & 1;
    const int w7   = gid & 127;
    const int chunk= w7 >> 4;             // 0..7
    const int wv   = w7 & 15;             // wave-in-group
    const int grp  = s2*8 + chunk;        // 0..31
    const int b0   = chunk*16;
    float* o = sent ? o2 : o1;
    const float* xgs = xg + (size_t)sent * MS * NCOL;
    const bf16_t* bb = whhB + (size_t)dr * (1024*HID);
    bf16_t* hxg = hx + (size_t)grp * 2 * 4096;
    int* flg = flags + grp*16;

    // ---- load the full B slice into VGPRs: gate g, unit col wv*16+l15
    bf16x8 bwc[4][8];
#pragma unroll
    for (int g = 0; g < 4; ++g) {
        const bf16_t* cp = bb + (size_t)(g*256 + wv*16 + l15)*HID + quad*8;
#pragma unroll
        for (int ks = 0; ks < 8; ++ks)
            bwc[g][ks] = *(const bf16x8*)(cp + ks*32);
    }

    float cst[4] = {0.0f, 0.0f, 0.0f, 0.0f};

    for (int t = 0; t < L_SEQ; ++t) {
        const int lt = dr ? (L_SEQ-1-t) : t;

        // xg for this step (independent of h -> issues early, consumed late)
        float xgv[4][4];
#pragma unroll
        for (int g = 0; g < 4; ++g) {
            const float* xp = xgs + (size_t)(lt*NB + b0 + quad*4)*NCOL
                              + dr*G4 + g*256 + wv*16 + l15;
#pragma unroll
            for (int r = 0; r < 4; ++r)
                xgv[g][r] = xp[(size_t)r*NCOL];
        }

        floatx4 acc[4] = {};
        if (t > 0) {
            // wait for all 16 peers to have published h_t
            int v;
            do {
                v = (lane < 16)
                    ? __hip_atomic_load(flg + lane, __ATOMIC_RELAXED,
                                        __HIP_MEMORY_SCOPE_AGENT)
                    : t;
            } while (!__all(v >= t));
            __threadfence();

            const bf16_t* fr = hxg + (t & 1)*4096;
#pragma unroll
            for (int ks = 0; ks < 8; ++ks) {
                bf16x8 af = *(const bf16x8*)(fr + ((ks*4 + quad)*16 + l15)*8);
#pragma unroll
                for (int g = 0; g < 4; ++g)
                    acc[g] = __builtin_amdgcn_mfma_f32_16x16x32_bf16(
                                 af, bwc[g][ks], acc[g], 0, 0, 0);
            }
        }

        // epilogue: rows m = quad*4+r, unit j = wv*16 + l15
        bf16_t* fw = hxg + ((t + 1) & 1)*4096;
#pragma unroll
        for (int r = 0; r < 4; ++r) {
            const int m = quad*4 + r;
            float gi = acc[0][r] + xgv[0][r];
            float gf = acc[1][r] + xgv[1][r];
            float gg = acc[2][r] + xgv[2][r];
            float go = acc[3][r] + xgv[3][r];
            float cv = fsigmoid(gf)*cst[r] + fsigmoid(gi)*ftanh(gg);
            cst[r] = cv;
            float hv = fsigmoid(go)*ftanh(cv);
            o[(size_t)(lt*NB + b0 + m)*DDIM + dr*HID + wv*16 + l15] = hv;
            // A-frag layout: unit kg = wv*16+l15 -> ((kg>>3)*16 + m)*8 + (kg&7)
            fw[((wv*2 + (l15 >> 3))*16 + m)*8 + (l15 & 7)] = (bf16_t)hv;
        }

        if (t < L_SEQ-1) {
            __threadfence();
            if (lane == 0)
                __hip_atomic_store(flg + wv, t + 1, __ATOMIC_RELAXED,
                                   __HIP_MEMORY_SCOPE_AGENT);
        }
    }
}

// ---------------------------------------------------------------------------
// mp1[b,d] = max_l o1[l,b,d]
// ---------------------------------------------------------------------------
__global__ __launch_bounds__(256) void k_mp1(const float* __restrict__ o1,
                                             float* __restrict__ mp1)
{
    int gid = blockIdx.x*256 + threadIdx.x;
    float m = -3.402823466e+38f;
    for (int l = 0; l < L_SEQ; ++l)
        m = fmaxf(m, o1[(size_t)l*(NB*DDIM) + gid]);
    mp1[gid] = m;
}

// ---------------------------------------------------------------------------
// attention + sim (unchanged)
// ---------------------------------------------------------------------------
__global__ __launch_bounds__(256) void k_att(const float* __restrict__ o2,
                                             const float* __restrict__ mp1,
                                             float* __restrict__ sim)
{
    const int b   = blockIdx.x;
    const int tid = threadIdx.x;
    const int l   = tid & 63;
    const int cp  = tid >> 6;
    __shared__ float spart[256];
    __shared__ float satt[64], sexp[64], ssm[64];
    __shared__ float red[256];

    const float* o2b = o2  + (size_t)b*32768;
    const float* mpb = mp1 + b*DDIM;

    float p = 0.0f;
    for (int d = cp*128; d < cp*128 + 128; ++d)
        p += mpb[d] * o2b[d*64 + l];
    spart[tid] = p;
    __syncthreads();
    if (tid < 64)
        satt[tid] = spart[tid] + spart[tid+64] + spart[tid+128] + spart[tid+192];
    __syncthreads();
    if (tid < 64) {
        float mx = satt[0];
        for (int i = 1; i < 64; ++i) mx = fmaxf(mx, satt[i]);
        sexp[tid] = expf(satt[tid] - mx);
    }
    __syncthreads();
    if (tid < 64) {
        float s = 0.0f;
        for (int i = 0; i < 64; ++i) s += sexp[i];
        ssm[tid] = sexp[tid] / s;
    }
    __syncthreads();

    float np0 = 0.0f, np1 = 0.0f;
    for (int l2 = 0; l2 < 64; ++l2) {
        float smv = ssm[l2];
        np0 += smv * o2b[l2*DDIM + tid];
        np1 += smv * o2b[l2*DDIM + tid + 256];
    }
    float diff = fabsf(mpb[tid] - np0) + fabsf(mpb[tid+256] - np1);
    red[tid] = diff;
    __syncthreads();
    for (int s = 128; s > 0; s >>= 1) {
        if (tid < s) red[tid] += red[tid + s];
        __syncthreads();
    }
    if (tid == 0) sim[b] = expf(-red[0]);
}

// ---------------------------------------------------------------------------
// commonWords + masked maxes (unchanged)
// ---------------------------------------------------------------------------
__global__ __launch_bounds__(256) void k_common(
    const int*   __restrict__ t1, const int* __restrict__ t2,
    const float* __restrict__ o1, const float* __restrict__ o2,
    float* __restrict__ e1h, float* __restrict__ e2h)
{
    const int b   = blockIdx.x;
    const int tid = threadIdx.x;
    __shared__ int ss1[64];
    __shared__ int smask[64];
    __shared__ int spos[64];
    __shared__ int sany;
    if (tid == 0) sany = 0;
    if (tid < 64) ss1[tid] = t1[tid*NB + b];
    __syncthreads();
    if (tid < 64) {
        int s2 = t2[tid*NB + b];
        int dmax = -1;
        for (int j = 0; j < 64; ++j)
            if (ss1[j] == s2) dmax = j;
        int mk = (dmax > 1) && (s2 > 0);
        smask[tid] = mk;
        spos[tid]  = dmax < 0 ? 0 : dmax;
        if (mk) sany = 1;
    }
    __syncthreads();
    int has = sany;
#pragma unroll
    for (int half = 0; half < 2; ++half) {
        int dd = tid + half*256;
        float m1 = -3.402823466e+38f, m2 = -3.402823466e+38f;
        for (int i = 0; i < 64; ++i) {
            if (smask[i]) {
                m1 = fmaxf(m1, o1[(size_t)spos[i]*(NB*DDIM) + b*DDIM + dd]);
                m2 = fmaxf(m2, o2[(size_t)i      *(NB*DDIM) + b*DDIM + dd]);
            }
        }
        e1h[b*DDIM + dd] = has ? m1 : 0.0f;
        e2h[b*DDIM + dd] = has ? m2 : 0.0f;
    }
}

// ---------------------------------------------------------------------------
extern "C" void kernel_launch(void* const* d_in, const int* in_sizes, int n_in,
                              void* d_out, int out_size, void* d_ws, size_t ws_size,
                              hipStream_t stream)
{
    (void)in_sizes; (void)n_in; (void)out_size; (void)ws_size;
    const int*   t1    = (const int*)d_in[0];
    const int*   t2    = (const int*)d_in[1];
    const float* emb   = (const float*)d_in[2];
    const float* wih_f = (const float*)d_in[3];
    const float* whh_f = (const float*)d_in[4];
    const float* bih_f = (const float*)d_in[5];
    const float* bhh_f = (const float*)d_in[6];
    const float* wih_b = (const float*)d_in[7];
    const float* whh_b = (const float*)d_in[8];
    const float* bih_b = (const float*)d_in[9];
    const float* bhh_b = (const float*)d_in[10];
    float* out = (float*)d_out;

    char* ws = (char*)d_ws;
    size_t off = 0;
    auto carve = [&](size_t bytes) -> void* {
        void* p = ws + off;
        off = (off + bytes + 255) & ~(size_t)255;
        return p;
    };
    float*  o1    = (float*)carve(sizeof(float)*(size_t)L_SEQ*NB*DDIM);
    float*  o2    = (float*)carve(sizeof(float)*(size_t)L_SEQ*NB*DDIM);
    bf16_t* whhB  = (bf16_t*)carve(sizeof(bf16_t)*2*1024*HID);
    bf16_t* Bw    = (bf16_t*)carve(sizeof(bf16_t)*(size_t)NCOL*EMBD);
    float*  bias  = (float*)carve(sizeof(float)*NCOL);
    float*  mp1   = (float*)carve(sizeof(float)*NB*DDIM);
    bf16_t* hx    = (bf16_t*)carve(sizeof(bf16_t)*32*2*4096);   // 512 KB
    int*    flags = (int*)carve(sizeof(int)*32*16);             // 2 KB
    float*  xgb   = (float*)carve(sizeof(float)*(size_t)MTOT*NCOL);  // 134 MB
    bf16_t* A     = (bf16_t*)o1;   // A dead before scan writes o1

    // flags must be 0 at scan start (ws is re-poisoned 0xAA before each launch)
    hipMemsetAsync(flags, 0, sizeof(int)*32*16, stream);

    hipLaunchKernelGGL(k_pack_a,    dim3(4096), dim3(256), 0, stream, t1, t2, emb, A);
    hipLaunchKernelGGL(k_pack_b,    dim3(512),  dim3(256), 0, stream, wih_f, wih_b, Bw);
    hipLaunchKernelGGL(k_pack_whh,  dim3(256),  dim3(256), 0, stream, whh_f, whh_b, whhB);
    hipLaunchKernelGGL(k_pack_bias, dim3(8),    dim3(256), 0, stream,
                       bih_f, bhh_f, bih_b, bhh_b, bias);

    hipLaunchKernelGGL(xg_gemm2, dim3(16, 128), dim3(256), 0, stream, A, Bw, bias, xgb);

    hipLaunchKernelGGL(lstm_scan4, dim3(512), dim3(64), 0, stream,
                       whhB, xgb, o1, o2, hx, flags);

    hipLaunchKernelGGL(k_mp1,    dim3(256), dim3(256), 0, stream, o1, mp1);
    hipLaunchKernelGGL(k_att,    dim3(128), dim3(256), 0, stream, o2, mp1, out);
    hipLaunchKernelGGL(k_common, dim3(128), dim3(256), 0, stream,
                       t1, t2, o1, o2, out + NB, out + NB + NB*DDIM);
}

// Round 5
// 834.531 us; speedup vs baseline: 2.7444x; 2.7444x over previous
//
#include <hip/hip_runtime.h>
#include <hip/hip_bf16.h>
#include <math.h>

#define L_SEQ 64
#define NB    128
#define EMBD  512
#define HID   256
#define G4    1024      // 4*HID
#define NCOL  2048      // 2 dirs * 4H
#define DDIM  512       // 2*HID
#define MS    (L_SEQ*NB)   // 8192 rows per sentence
#define MTOT  (2*MS)       // 16384 combined rows

typedef __bf16 bf16_t;
typedef bf16_t bf16x4 __attribute__((ext_vector_type(4)));
typedef bf16_t bf16x8 __attribute__((ext_vector_type(8)));
typedef float  floatx4 __attribute__((ext_vector_type(4)));
typedef float  floatx8 __attribute__((ext_vector_type(8)));

__device__ __forceinline__ bf16x8 cvt_bf16x8(floatx8 v) {
    bf16x8 r;
    r[0]=(bf16_t)v[0]; r[1]=(bf16_t)v[1]; r[2]=(bf16_t)v[2]; r[3]=(bf16_t)v[3];
    r[4]=(bf16_t)v[4]; r[5]=(bf16_t)v[5]; r[6]=(bf16_t)v[6]; r[7]=(bf16_t)v[7];
    return r;
}

__device__ __forceinline__ void gload_lds16(const bf16_t* g, bf16_t* l) {
    __builtin_amdgcn_global_load_lds(
        (const __attribute__((address_space(1))) unsigned int*)(g),
        (__attribute__((address_space(3))) unsigned int*)(l), 16, 0, 0);
}

__device__ __forceinline__ float fsigmoid(float x) {
    return __builtin_amdgcn_rcpf(1.0f + __expf(-x));
}
__device__ __forceinline__ float ftanh(float x) {
    return 1.0f - 2.0f * __builtin_amdgcn_rcpf(__expf(2.0f*x) + 1.0f);
}

// ---------------------------------------------------------------------------
// Pack kernels (unchanged)
// ---------------------------------------------------------------------------
__global__ __launch_bounds__(256) void k_pack_a(const int* __restrict__ t1,
                                                const int* __restrict__ t2,
                                                const float* __restrict__ emb,
                                                bf16_t* __restrict__ A)
{
    int gid = blockIdx.x*256 + threadIdx.x;
    int row = gid >> 6;
    int k8  = (gid & 63) * 8;
    int tok = (row < MS) ? t1[row] : t2[row - MS];
    floatx8 v = *(const floatx8*)(emb + (size_t)tok*EMBD + k8);
    *(bf16x8*)(A + (size_t)row*EMBD + k8) = cvt_bf16x8(v);
}

__global__ __launch_bounds__(256) void k_pack_b(const float* __restrict__ wih_f,
                                                const float* __restrict__ wih_b,
                                                bf16_t* __restrict__ B)
{
    int gid = blockIdx.x*256 + threadIdx.x;
    int n   = gid >> 6;
    int k8  = (gid & 63) * 8;
    const float* src = (n >= 1024) ? (wih_b + (size_t)(n-1024)*EMBD)
                                   : (wih_f + (size_t)n*EMBD);
    *(bf16x8*)(B + (size_t)n*EMBD + k8) = cvt_bf16x8(*(const floatx8*)(src + k8));
}

__global__ __launch_bounds__(256) void k_pack_whh(const float* __restrict__ whh_f,
                                                  const float* __restrict__ whh_b,
                                                  bf16_t* __restrict__ whhB)
{
    int gid = blockIdx.x*256 + threadIdx.x;
    int r2  = gid >> 5;
    int k8  = (gid & 31) * 8;
    const float* src = (r2 >= 1024) ? (whh_b + (size_t)(r2-1024)*HID)
                                    : (whh_f + (size_t)r2*HID);
    *(bf16x8*)(whhB + (size_t)r2*HID + k8) = cvt_bf16x8(*(const floatx8*)(src + k8));
}

__global__ __launch_bounds__(256) void k_pack_bias(const float* __restrict__ bih_f,
                                                   const float* __restrict__ bhh_f,
                                                   const float* __restrict__ bih_b,
                                                   const float* __restrict__ bhh_b,
                                                   float* __restrict__ bias)
{
    int n = blockIdx.x*256 + threadIdx.x;
    bias[n] = (n >= 1024) ? (bih_b[n-1024] + bhh_b[n-1024])
                          : (bih_f[n] + bhh_f[n]);
}

// ---------------------------------------------------------------------------
// xg GEMM v3: same MFMA core as v2, but epilogue stores bf16 TRANSPOSED:
//   xgT[((s2*64 + l)*1024 + gcol)*128 + b],  s2 = sent*2 + dir
// so the scan reads contiguous batch-vectors. Each block covers exactly one
// (sent, l) since M-tiles are 128-aligned.
// ---------------------------------------------------------------------------
__global__ __launch_bounds__(256) void xg_gemm3(const bf16_t* __restrict__ A,
                                                const bf16_t* __restrict__ B,
                                                const float* __restrict__ bias,
                                                bf16_t* __restrict__ xgT)
{
    __shared__ bf16_t As[128*32];
    __shared__ bf16_t Bs[128*32];
    const int tid  = threadIdx.x;
    const int wid  = tid >> 6;
    const int lane = tid & 63;
    const int l15  = lane & 15;
    const int quad = lane >> 4;
    const int m0   = blockIdx.y * 128;
    const int n0   = blockIdx.x * 128;
    const int mw   = (wid & 1) * 64;
    const int nw   = (wid >> 1) * 64;

    float biasv[4];
#pragma unroll
    for (int ni = 0; ni < 4; ++ni) biasv[ni] = bias[n0 + nw + ni*16 + l15];

    const int srow = tid >> 2;
    const int sk8  = (tid & 3) * 8;

    floatx4 acc[4][4] = {};
    for (int kk = 0; kk < EMBD; kk += 32) {
#pragma unroll
        for (int inst = 0; inst < 2; ++inst) {
            gload_lds16(A + (size_t)(m0 + inst*64 + srow)*EMBD + kk + sk8,
                        As + inst*2048 + wid*512);
            gload_lds16(B + (size_t)(n0 + inst*64 + srow)*EMBD + kk + sk8,
                        Bs + inst*2048 + wid*512);
        }
        __syncthreads();
        bf16x8 a[4], b[4];
#pragma unroll
        for (int mi = 0; mi < 4; ++mi)
            a[mi] = *(const bf16x8*)(As + (mw + mi*16 + l15)*32 + quad*8);
#pragma unroll
        for (int ni = 0; ni < 4; ++ni)
            b[ni] = *(const bf16x8*)(Bs + (nw + ni*16 + l15)*32 + quad*8);
#pragma unroll
        for (int mi = 0; mi < 4; ++mi)
#pragma unroll
            for (int ni = 0; ni < 4; ++ni)
                acc[mi][ni] = __builtin_amdgcn_mfma_f32_16x16x32_bf16(
                                  a[mi], b[ni], acc[mi][ni], 0, 0, 0);
        __syncthreads();
    }

    // epilogue: transpose-store bf16
    const int sent = blockIdx.y >> 6;       // m = sent*8192 + l*128 + b
    const int l    = blockIdx.y & 63;
    const int dir  = n0 >> 10;              // uniform per block (128 | 1024)
    const int s2   = sent*2 + dir;
    bf16_t* outb = xgT + (size_t)(s2*64 + l)*1024*128;
#pragma unroll
    for (int mi = 0; mi < 4; ++mi)
#pragma unroll
        for (int ni = 0; ni < 4; ++ni) {
            int gcol = (n0 & 1023) + nw + ni*16 + l15;
            int b    = mw + mi*16 + quad*4;
            bf16x4 v;
#pragma unroll
            for (int r = 0; r < 4; ++r) v[r] = (bf16_t)(acc[mi][ni][r] + biasv[ni]);
            *(bf16x4*)(outb + (size_t)gcol*128 + b) = v;
        }
}

// ---------------------------------------------------------------------------
// LSTM scan v5: R4's wave decomposition, regrouped into one block per
// (stream, batch-chunk-of-16) with LDS h exchange.
// Grid (8 chunks, 4 streams) x 1024 threads (16 waves).
// Wave wv owns hidden units [wv*16,+16) x 4 gates: its Whh slice (32 KB)
// lives entirely in VGPRs (128 regs) -> zero per-step weight traffic.
// h ping-pong in LDS (2 x 8 KB, A-frag layout, conflict-free b128 reads);
// ONE __syncthreads per step. t=0 skips the MFMA (h0 = 0).
// ---------------------------------------------------------------------------
__global__ __launch_bounds__(1024, 4) void lstm_scan5(
    const bf16_t* __restrict__ whhB,   // [2][1024][256] bf16
    const bf16_t* __restrict__ xgT,    // [4][64][1024][128] bf16
    float* __restrict__ o1, float* __restrict__ o2)
{
    __shared__ bf16_t hb[2][4096];     // [frame][A-frag layout of 16x256]

    const int tid  = threadIdx.x;
    const int wv   = tid >> 6;            // 0..15
    const int lane = tid & 63;
    const int l15  = lane & 15;
    const int quad = lane >> 4;
    const int s2   = blockIdx.y;          // sent*2 + dr
    const int sent = s2 >> 1;
    const int dr   = s2 & 1;
    const int b0   = blockIdx.x * 16;
    float* o = sent ? o2 : o1;
    const bf16_t* bb = whhB + (size_t)dr * (1024*HID);

    // ---- full Whh slice into VGPRs: gate g, unit col wv*16+l15
    bf16x8 bwc[4][8];
#pragma unroll
    for (int g = 0; g < 4; ++g) {
        const bf16_t* cp = bb + (size_t)(g*256 + wv*16 + l15)*HID + quad*8;
#pragma unroll
        for (int ks = 0; ks < 8; ++ks)
            bwc[g][ks] = *(const bf16x8*)(cp + ks*32);
    }

    const int j = wv*16 + l15;            // owned hidden unit
    float cst[4] = {0.0f, 0.0f, 0.0f, 0.0f};

    for (int t = 0; t < L_SEQ; ++t) {
        const int lt = dr ? (L_SEQ-1-t) : t;

        // xg for this step: contiguous batch-vectors (independent of h)
        const bf16_t* xp = xgT + (size_t)(s2*64 + lt)*1024*128;
        bf16x4 xv[4];
#pragma unroll
        for (int g = 0; g < 4; ++g)
            xv[g] = *(const bf16x4*)(xp + (size_t)(g*256 + j)*128 + b0 + quad*4);

        floatx4 acc[4] = {};
        if (t > 0) {
            const bf16_t* fr = hb[t & 1];
#pragma unroll
            for (int ks = 0; ks < 8; ++ks) {
                bf16x8 af = *(const bf16x8*)(fr + ((ks*4 + quad)*16 + l15)*8);
#pragma unroll
                for (int g = 0; g < 4; ++g)
                    acc[g] = __builtin_amdgcn_mfma_f32_16x16x32_bf16(
                                 af, bwc[g][ks], acc[g], 0, 0, 0);
            }
        }

        // epilogue: rows m = quad*4+r of this chunk, unit j
        bf16_t* fw = hb[(t + 1) & 1];
#pragma unroll
        for (int r = 0; r < 4; ++r) {
            const int m = quad*4 + r;
            float gi = acc[0][r] + (float)xv[0][r];
            float gf = acc[1][r] + (float)xv[1][r];
            float gg = acc[2][r] + (float)xv[2][r];
            float go = acc[3][r] + (float)xv[3][r];
            float cv = fsigmoid(gf)*cst[r] + fsigmoid(gi)*ftanh(gg);
            cst[r] = cv;
            float hv = fsigmoid(go)*ftanh(cv);
            o[(size_t)(lt*NB + b0 + m)*DDIM + dr*HID + j] = hv;
            // A-frag layout: (m, k=j) -> ((j>>3)*16 + m)*8 + (j&7)
            fw[((j >> 3)*16 + m)*8 + (j & 7)] = (bf16_t)hv;
        }
        __syncthreads();
    }
}

// ---------------------------------------------------------------------------
// mp1[b,d] = max_l o1[l,b,d]
// ---------------------------------------------------------------------------
__global__ __launch_bounds__(256) void k_mp1(const float* __restrict__ o1,
                                             float* __restrict__ mp1)
{
    int gid = blockIdx.x*256 + threadIdx.x;
    float m = -3.402823466e+38f;
    for (int l = 0; l < L_SEQ; ++l)
        m = fmaxf(m, o1[(size_t)l*(NB*DDIM) + gid]);
    mp1[gid] = m;
}

// ---------------------------------------------------------------------------
// attention + sim (unchanged)
// ---------------------------------------------------------------------------
__global__ __launch_bounds__(256) void k_att(const float* __restrict__ o2,
                                             const float* __restrict__ mp1,
                                             float* __restrict__ sim)
{
    const int b   = blockIdx.x;
    const int tid = threadIdx.x;
    const int l   = tid & 63;
    const int cp  = tid >> 6;
    __shared__ float spart[256];
    __shared__ float satt[64], sexp[64], ssm[64];
    __shared__ float red[256];

    const float* o2b = o2  + (size_t)b*32768;
    const float* mpb = mp1 + b*DDIM;

    float p = 0.0f;
    for (int d = cp*128; d < cp*128 + 128; ++d)
        p += mpb[d] * o2b[d*64 + l];
    spart[tid] = p;
    __syncthreads();
    if (tid < 64)
        satt[tid] = spart[tid] + spart[tid+64] + spart[tid+128] + spart[tid+192];
    __syncthreads();
    if (tid < 64) {
        float mx = satt[0];
        for (int i = 1; i < 64; ++i) mx = fmaxf(mx, satt[i]);
        sexp[tid] = expf(satt[tid] - mx);
    }
    __syncthreads();
    if (tid < 64) {
        float s = 0.0f;
        for (int i = 0; i < 64; ++i) s += sexp[i];
        ssm[tid] = sexp[tid] / s;
    }
    __syncthreads();

    float np0 = 0.0f, np1 = 0.0f;
    for (int l2 = 0; l2 < 64; ++l2) {
        float smv = ssm[l2];
        np0 += smv * o2b[l2*DDIM + tid];
        np1 += smv * o2b[l2*DDIM + tid + 256];
    }
    float diff = fabsf(mpb[tid] - np0) + fabsf(mpb[tid+256] - np1);
    red[tid] = diff;
    __syncthreads();
    for (int s = 128; s > 0; s >>= 1) {
        if (tid < s) red[tid] += red[tid + s];
        __syncthreads();
    }
    if (tid == 0) sim[b] = expf(-red[0]);
}

// ---------------------------------------------------------------------------
// commonWords + masked maxes (unchanged)
// ---------------------------------------------------------------------------
__global__ __launch_bounds__(256) void k_common(
    const int*   __restrict__ t1, const int* __restrict__ t2,
    const float* __restrict__ o1, const float* __restrict__ o2,
    float* __restrict__ e1h, float* __restrict__ e2h)
{
    const int b   = blockIdx.x;
    const int tid = threadIdx.x;
    __shared__ int ss1[64];
    __shared__ int smask[64];
    __shared__ int spos[64];
    __shared__ int sany;
    if (tid == 0) sany = 0;
    if (tid < 64) ss1[tid] = t1[tid*NB + b];
    __syncthreads();
    if (tid < 64) {
        int s2 = t2[tid*NB + b];
        int dmax = -1;
        for (int j = 0; j < 64; ++j)
            if (ss1[j] == s2) dmax = j;
        int mk = (dmax > 1) && (s2 > 0);
        smask[tid] = mk;
        spos[tid]  = dmax < 0 ? 0 : dmax;
        if (mk) sany = 1;
    }
    __syncthreads();
    int has = sany;
#pragma unroll
    for (int half = 0; half < 2; ++half) {
        int dd = tid + half*256;
        float m1 = -3.402823466e+38f, m2 = -3.402823466e+38f;
        for (int i = 0; i < 64; ++i) {
            if (smask[i]) {
                m1 = fmaxf(m1, o1[(size_t)spos[i]*(NB*DDIM) + b*DDIM + dd]);
                m2 = fmaxf(m2, o2[(size_t)i      *(NB*DDIM) + b*DDIM + dd]);
            }
        }
        e1h[b*DDIM + dd] = has ? m1 : 0.0f;
        e2h[b*DDIM + dd] = has ? m2 : 0.0f;
    }
}

// ---------------------------------------------------------------------------
extern "C" void kernel_launch(void* const* d_in, const int* in_sizes, int n_in,
                              void* d_out, int out_size, void* d_ws, size_t ws_size,
                              hipStream_t stream)
{
    (void)in_sizes; (void)n_in; (void)out_size; (void)ws_size;
    const int*   t1    = (const int*)d_in[0];
    const int*   t2    = (const int*)d_in[1];
    const float* emb   = (const float*)d_in[2];
    const float* wih_f = (const float*)d_in[3];
    const float* whh_f = (const float*)d_in[4];
    const float* bih_f = (const float*)d_in[5];
    const float* bhh_f = (const float*)d_in[6];
    const float* wih_b = (const float*)d_in[7];
    const float* whh_b = (const float*)d_in[8];
    const float* bih_b = (const float*)d_in[9];
    const float* bhh_b = (const float*)d_in[10];
    float* out = (float*)d_out;

    char* ws = (char*)d_ws;
    size_t off = 0;
    auto carve = [&](size_t bytes) -> void* {
        void* p = ws + off;
        off = (off + bytes + 255) & ~(size_t)255;
        return p;
    };
    float*  o1    = (float*)carve(sizeof(float)*(size_t)L_SEQ*NB*DDIM);
    float*  o2    = (float*)carve(sizeof(float)*(size_t)L_SEQ*NB*DDIM);
    bf16_t* whhB  = (bf16_t*)carve(sizeof(bf16_t)*2*1024*HID);
    bf16_t* Bw    = (bf16_t*)carve(sizeof(bf16_t)*(size_t)NCOL*EMBD);
    float*  bias  = (float*)carve(sizeof(float)*NCOL);
    float*  mp1   = (float*)carve(sizeof(float)*NB*DDIM);
    bf16_t* xgT   = (bf16_t*)carve(sizeof(bf16_t)*(size_t)MTOT*NCOL);  // 67 MB
    bf16_t* A     = (bf16_t*)o1;   // A dead before scan writes o1

    hipLaunchKernelGGL(k_pack_a,    dim3(4096), dim3(256), 0, stream, t1, t2, emb, A);
    hipLaunchKernelGGL(k_pack_b,    dim3(512),  dim3(256), 0, stream, wih_f, wih_b, Bw);
    hipLaunchKernelGGL(k_pack_whh,  dim3(256),  dim3(256), 0, stream, whh_f, whh_b, whhB);
    hipLaunchKernelGGL(k_pack_bias, dim3(8),    dim3(256), 0, stream,
                       bih_f, bhh_f, bih_b, bhh_b, bias);

    hipLaunchKernelGGL(xg_gemm3, dim3(16, 128), dim3(256), 0, stream, A, Bw, bias, xgT);

    hipLaunchKernelGGL(lstm_scan5, dim3(8, 4), dim3(1024), 0, stream,
                       whhB, xgT, o1, o2);

    hipLaunchKernelGGL(k_mp1,    dim3(256), dim3(256), 0, stream, o1, mp1);
    hipLaunchKernelGGL(k_att,    dim3(128), dim3(256), 0, stream, o2, mp1, out);
    hipLaunchKernelGGL(k_common, dim3(128), dim3(256), 0, stream,
                       t1, t2, o1, o2, out + NB, out + NB + NB*DDIM);
}

// Round 7
// 667.337 us; speedup vs baseline: 3.4320x; 1.2505x over previous
//
#include <hip/hip_runtime.h>
#include <hip/hip_bf16.h>
#include <math.h>

#define L_SEQ 64
#define NB    128
#define EMBD  512
#define HID   256
#define G4    1024      // 4*HID
#define NCOL  2048      // 2 dirs * 4H
#define DDIM  512       // 2*HID
#define MS    (L_SEQ*NB)   // 8192 rows per sentence
#define MTOT  (2*MS)       // 16384 combined rows

typedef __bf16 bf16_t;
typedef bf16_t bf16x4 __attribute__((ext_vector_type(4)));
typedef bf16_t bf16x8 __attribute__((ext_vector_type(8)));
typedef float  floatx4 __attribute__((ext_vector_type(4)));
typedef float  floatx8 __attribute__((ext_vector_type(8)));

__device__ __forceinline__ bf16x8 cvt_bf16x8(floatx8 v) {
    bf16x8 r;
    r[0]=(bf16_t)v[0]; r[1]=(bf16_t)v[1]; r[2]=(bf16_t)v[2]; r[3]=(bf16_t)v[3];
    r[4]=(bf16_t)v[4]; r[5]=(bf16_t)v[5]; r[6]=(bf16_t)v[6]; r[7]=(bf16_t)v[7];
    return r;
}

__device__ __forceinline__ void gload_lds16(const bf16_t* g, bf16_t* l) {
    __builtin_amdgcn_global_load_lds(
        (const __attribute__((address_space(1))) unsigned int*)(g),
        (__attribute__((address_space(3))) unsigned int*)(l), 16, 0, 0);
}

__device__ __forceinline__ float fsigmoid(float x) {
    return __builtin_amdgcn_rcpf(1.0f + __expf(-x));
}
__device__ __forceinline__ float ftanh(float x) {
    return 1.0f - 2.0f * __builtin_amdgcn_rcpf(__expf(2.0f*x) + 1.0f);
}

// ---------------------------------------------------------------------------
// Pack kernels (unchanged)
// ---------------------------------------------------------------------------
__global__ __launch_bounds__(256) void k_pack_a(const int* __restrict__ t1,
                                                const int* __restrict__ t2,
                                                const float* __restrict__ emb,
                                                bf16_t* __restrict__ A)
{
    int gid = blockIdx.x*256 + threadIdx.x;
    int row = gid >> 6;
    int k8  = (gid & 63) * 8;
    int tok = (row < MS) ? t1[row] : t2[row - MS];
    floatx8 v = *(const floatx8*)(emb + (size_t)tok*EMBD + k8);
    *(bf16x8*)(A + (size_t)row*EMBD + k8) = cvt_bf16x8(v);
}

__global__ __launch_bounds__(256) void k_pack_b(const float* __restrict__ wih_f,
                                                const float* __restrict__ wih_b,
                                                bf16_t* __restrict__ B)
{
    int gid = blockIdx.x*256 + threadIdx.x;
    int n   = gid >> 6;
    int k8  = (gid & 63) * 8;
    const float* src = (n >= 1024) ? (wih_b + (size_t)(n-1024)*EMBD)
                                   : (wih_f + (size_t)n*EMBD);
    *(bf16x8*)(B + (size_t)n*EMBD + k8) = cvt_bf16x8(*(const floatx8*)(src + k8));
}

__global__ __launch_bounds__(256) void k_pack_whh(const float* __restrict__ whh_f,
                                                  const float* __restrict__ whh_b,
                                                  bf16_t* __restrict__ whhB)
{
    int gid = blockIdx.x*256 + threadIdx.x;
    int r2  = gid >> 5;
    int k8  = (gid & 31) * 8;
    const float* src = (r2 >= 1024) ? (whh_b + (size_t)(r2-1024)*HID)
                                    : (whh_f + (size_t)r2*HID);
    *(bf16x8*)(whhB + (size_t)r2*HID + k8) = cvt_bf16x8(*(const floatx8*)(src + k8));
}

__global__ __launch_bounds__(256) void k_pack_bias(const float* __restrict__ bih_f,
                                                   const float* __restrict__ bhh_f,
                                                   const float* __restrict__ bih_b,
                                                   const float* __restrict__ bhh_b,
                                                   float* __restrict__ bias)
{
    int n = blockIdx.x*256 + threadIdx.x;
    bias[n] = (n >= 1024) ? (bih_b[n-1024] + bhh_b[n-1024])
                          : (bih_f[n] + bhh_f[n]);
}

// ---------------------------------------------------------------------------
// xg GEMM v4 (unchanged from R6): epilogue stores bf16 per-chunk layout
//   xgT[(((s2*8 + ch)*64 + l)*1024 + gcol)*16 + bi],  ch=b>>4, bi=b&15
// ---------------------------------------------------------------------------
__global__ __launch_bounds__(256) void xg_gemm4(const bf16_t* __restrict__ A,
                                                const bf16_t* __restrict__ B,
                                                const float* __restrict__ bias,
                                                bf16_t* __restrict__ xgT)
{
    __shared__ bf16_t As[128*32];
    __shared__ bf16_t Bs[128*32];
    const int tid  = threadIdx.x;
    const int wid  = tid >> 6;
    const int lane = tid & 63;
    const int l15  = lane & 15;
    const int quad = lane >> 4;
    const int m0   = blockIdx.y * 128;
    const int n0   = blockIdx.x * 128;
    const int mw   = (wid & 1) * 64;
    const int nw   = (wid >> 1) * 64;

    float biasv[4];
#pragma unroll
    for (int ni = 0; ni < 4; ++ni) biasv[ni] = bias[n0 + nw + ni*16 + l15];

    const int srow = tid >> 2;
    const int sk8  = (tid & 3) * 8;

    floatx4 acc[4][4] = {};
    for (int kk = 0; kk < EMBD; kk += 32) {
#pragma unroll
        for (int inst = 0; inst < 2; ++inst) {
            gload_lds16(A + (size_t)(m0 + inst*64 + srow)*EMBD + kk + sk8,
                        As + inst*2048 + wid*512);
            gload_lds16(B + (size_t)(n0 + inst*64 + srow)*EMBD + kk + sk8,
                        Bs + inst*2048 + wid*512);
        }
        __syncthreads();
        bf16x8 a[4], b[4];
#pragma unroll
        for (int mi = 0; mi < 4; ++mi)
            a[mi] = *(const bf16x8*)(As + (mw + mi*16 + l15)*32 + quad*8);
#pragma unroll
        for (int ni = 0; ni < 4; ++ni)
            b[ni] = *(const bf16x8*)(Bs + (nw + ni*16 + l15)*32 + quad*8);
#pragma unroll
        for (int mi = 0; mi < 4; ++mi)
#pragma unroll
            for (int ni = 0; ni < 4; ++ni)
                acc[mi][ni] = __builtin_amdgcn_mfma_f32_16x16x32_bf16(
                                  a[mi], b[ni], acc[mi][ni], 0, 0, 0);
        __syncthreads();
    }

    // epilogue: per-chunk transposed bf16 store
    const int sent = blockIdx.y >> 6;       // m = sent*8192 + l*128 + b
    const int l    = blockIdx.y & 63;
    const int dir  = n0 >> 10;              // uniform per block
    const int s2   = sent*2 + dir;
#pragma unroll
    for (int mi = 0; mi < 4; ++mi)
#pragma unroll
        for (int ni = 0; ni < 4; ++ni) {
            int gcol = (n0 & 1023) + nw + ni*16 + l15;
            int b    = mw + mi*16 + quad*4;
            int ch   = b >> 4;
            int bi   = b & 15;
            bf16x4 v;
#pragma unroll
            for (int r = 0; r < 4; ++r) v[r] = (bf16_t)(acc[mi][ni][r] + biasv[ni]);
            *(bf16x4*)(xgT + ((size_t)((s2*8 + ch)*64 + l)*1024 + gcol)*16 + bi) = v;
        }
}

// ---------------------------------------------------------------------------
// LSTM scan v6b: R6 structure with the LDS frag-stride bug FIXED.
// A weight frag = 64 lanes x 16 B = 1024 B = 512 bf16 elements; BL frags are
// spaced 512 ELEMENTS apart (R6 wrongly used 1024 -> upper half OOB/dropped).
//   ks0..3  VGPR-resident (32 frags, 128 regs; volatile loads -> no remat)
//   ks4..5  LDS-resident  (128 frags x 1 KB = 128 KB, preloaded once)
//   ks6..7  streamed per step (batched; <=32 streamed regs live)
// ---------------------------------------------------------------------------
__global__ __launch_bounds__(512, 2) void lstm_scan6(
    const bf16_t* __restrict__ whhB,   // [2][1024][256] bf16
    const bf16_t* __restrict__ xgT,    // per-chunk layout
    float* __restrict__ o1, float* __restrict__ o2)
{
    extern __shared__ char smem[];
    bf16_t* hb = (bf16_t*)smem;              // 2 frames x 4096 bf16 = 16 KB
    bf16_t* BL = (bf16_t*)(smem + 16384);    // 128 frags x 512 bf16 = 128 KB

    const int tid  = threadIdx.x;
    const int wv   = tid >> 6;            // 0..7
    const int lane = tid & 63;
    const int l15  = lane & 15;
    const int quad = lane >> 4;
    const int s2   = blockIdx.y;          // sent*2 + dr
    const int sent = s2 >> 1;
    const int dr   = s2 & 1;
    const int chunk= blockIdx.x;
    const int b0   = chunk * 16;
    float* o = sent ? o2 : o1;
    const bf16_t* bb = whhB + (size_t)dr * (1024*HID);

    // ---- LDS weight preload: ks 4,5 for all 8 nt (nt = gate*2 + unit-half)
    // frag stride = 512 elements (1024 bytes)  <-- FIX
#pragma unroll
    for (int nt = 0; nt < 8; ++nt) {
        const int g = nt >> 1, u = nt & 1;
        const int col = g*256 + wv*32 + u*16 + l15;
#pragma unroll
        for (int ksl = 0; ksl < 2; ++ksl)
            gload_lds16(bb + (size_t)col*HID + (4+ksl)*32 + quad*8,
                        BL + (size_t)(wv*16 + nt*2 + ksl)*512);
    }

    // ---- VGPR weights ks0..3 — volatile loads: compiler cannot rematerialize
    bf16x8 bwc[8][4];
#pragma unroll
    for (int nt = 0; nt < 8; ++nt) {
        const int g = nt >> 1, u = nt & 1;
        const bf16_t* cp = bb + (size_t)(g*256 + wv*32 + u*16 + l15)*HID + quad*8;
#pragma unroll
        for (int ks = 0; ks < 4; ++ks)
            bwc[nt][ks] = *(const volatile bf16x8*)(cp + ks*32);
    }

    // zero h frame 0
    for (int i = tid; i < 4096; i += 512) hb[i] = (bf16_t)0.0f;
    __syncthreads();   // also drains gload_lds

    float cst[2][4] = {};
    int pp = 0;

    for (int t = 0; t < L_SEQ; ++t) {
        const int lt = dr ? (L_SEQ-1-t) : t;
        asm volatile("" ::: "memory");   // keep in-loop loads in-loop

        // xg for this step: dense 32 KB block, coalesced, consumed in epilogue
        const bf16_t* xp = xgT + (size_t)((s2*8 + chunk)*64 + lt)*16384;
        bf16x4 xv[8];
#pragma unroll
        for (int nt = 0; nt < 8; ++nt) {
            const int g = nt >> 1, u = nt & 1;
            xv[nt] = *(const bf16x4*)(xp + (size_t)(g*256 + wv*32 + u*16 + l15)*16
                                      + quad*4);
        }

        floatx4 acc[8] = {};
        if (t > 0) {
            // streamed ks6 batch (8 frags, 32 regs), issued before the MFMA body
            bf16x8 sb[8];
#pragma unroll
            for (int nt = 0; nt < 8; ++nt) {
                const int g = nt >> 1, u = nt & 1;
                sb[nt] = *(const bf16x8*)(bb + (size_t)(g*256 + wv*32 + u*16 + l15)*HID
                                          + 6*32 + quad*8);
            }

            const bf16_t* fr = hb + pp*4096;
            // ks0..3: VGPR weights
#pragma unroll
            for (int ks = 0; ks < 4; ++ks) {
                bf16x8 af = *(const bf16x8*)(fr + ((ks*4 + quad)*16 + l15)*8);
#pragma unroll
                for (int nt = 0; nt < 8; ++nt)
                    acc[nt] = __builtin_amdgcn_mfma_f32_16x16x32_bf16(
                                  af, bwc[nt][ks], acc[nt], 0, 0, 0);
            }
            // ks4,5: LDS weights (frag stride 512 elements)  <-- FIX
#pragma unroll
            for (int ksl = 0; ksl < 2; ++ksl) {
                bf16x8 af = *(const bf16x8*)(fr + (((4+ksl)*4 + quad)*16 + l15)*8);
#pragma unroll
                for (int nt = 0; nt < 8; ++nt) {
                    bf16x8 bl = *(const bf16x8*)(BL + (size_t)(wv*16 + nt*2 + ksl)*512
                                                 + lane*8);
                    acc[nt] = __builtin_amdgcn_mfma_f32_16x16x32_bf16(
                                  af, bl, acc[nt], 0, 0, 0);
                }
            }
            // ks6: consume streamed batch
            {
                bf16x8 af = *(const bf16x8*)(fr + ((6*4 + quad)*16 + l15)*8);
#pragma unroll
                for (int nt = 0; nt < 8; ++nt)
                    acc[nt] = __builtin_amdgcn_mfma_f32_16x16x32_bf16(
                                  af, sb[nt], acc[nt], 0, 0, 0);
            }
            // ks7: reload streamed batch (regs reuse sb), consume
#pragma unroll
            for (int nt = 0; nt < 8; ++nt) {
                const int g = nt >> 1, u = nt & 1;
                sb[nt] = *(const bf16x8*)(bb + (size_t)(g*256 + wv*32 + u*16 + l15)*HID
                                          + 7*32 + quad*8);
            }
            {
                bf16x8 af = *(const bf16x8*)(fr + ((7*4 + quad)*16 + l15)*8);
#pragma unroll
                for (int nt = 0; nt < 8; ++nt)
                    acc[nt] = __builtin_amdgcn_mfma_f32_16x16x32_bf16(
                                  af, sb[nt], acc[nt], 0, 0, 0);
            }
        }

        // epilogue: rows m = quad*4+r, units j = wv*32 + u*16 + l15
        bf16_t* fw = hb + (pp^1)*4096;
#pragma unroll
        for (int u = 0; u < 2; ++u) {
            const int j = wv*32 + u*16 + l15;
            float* orow = o + (size_t)(lt*NB + b0)*DDIM + dr*HID + j;
#pragma unroll
            for (int r = 0; r < 4; ++r) {
                const int m = quad*4 + r;
                float gi = acc[0*2+u][r] + (float)xv[0*2+u][r];
                float gf = acc[1*2+u][r] + (float)xv[1*2+u][r];
                float gg = acc[2*2+u][r] + (float)xv[2*2+u][r];
                float go = acc[3*2+u][r] + (float)xv[3*2+u][r];
                float cv = fsigmoid(gf)*cst[u][r] + fsigmoid(gi)*ftanh(gg);
                cst[u][r] = cv;
                float hv = fsigmoid(go)*ftanh(cv);
                orow[(size_t)m*DDIM] = hv;
                fw[((j >> 3)*16 + m)*8 + (j & 7)] = (bf16_t)hv;
            }
        }
        __syncthreads();
        pp ^= 1;
    }
}

// ---------------------------------------------------------------------------
// mp1[b,d] = max_l o1[l,b,d]
// ---------------------------------------------------------------------------
__global__ __launch_bounds__(256) void k_mp1(const float* __restrict__ o1,
                                             float* __restrict__ mp1)
{
    int gid = blockIdx.x*256 + threadIdx.x;
    float m = -3.402823466e+38f;
    for (int l = 0; l < L_SEQ; ++l)
        m = fmaxf(m, o1[(size_t)l*(NB*DDIM) + gid]);
    mp1[gid] = m;
}

// ---------------------------------------------------------------------------
// attention + sim (unchanged)
// ---------------------------------------------------------------------------
__global__ __launch_bounds__(256) void k_att(const float* __restrict__ o2,
                                             const float* __restrict__ mp1,
                                             float* __restrict__ sim)
{
    const int b   = blockIdx.x;
    const int tid = threadIdx.x;
    const int l   = tid & 63;
    const int cp  = tid >> 6;
    __shared__ float spart[256];
    __shared__ float satt[64], sexp[64], ssm[64];
    __shared__ float red[256];

    const float* o2b = o2  + (size_t)b*32768;
    const float* mpb = mp1 + b*DDIM;

    float p = 0.0f;
    for (int d = cp*128; d < cp*128 + 128; ++d)
        p += mpb[d] * o2b[d*64 + l];
    spart[tid] = p;
    __syncthreads();
    if (tid < 64)
        satt[tid] = spart[tid] + spart[tid+64] + spart[tid+128] + spart[tid+192];
    __syncthreads();
    if (tid < 64) {
        float mx = satt[0];
        for (int i = 1; i < 64; ++i) mx = fmaxf(mx, satt[i]);
        sexp[tid] = expf(satt[tid] - mx);
    }
    __syncthreads();
    if (tid < 64) {
        float s = 0.0f;
        for (int i = 0; i < 64; ++i) s += sexp[i];
        ssm[tid] = sexp[tid] / s;
    }
    __syncthreads();

    float np0 = 0.0f, np1 = 0.0f;
    for (int l2 = 0; l2 < 64; ++l2) {
        float smv = ssm[l2];
        np0 += smv * o2b[l2*DDIM + tid];
        np1 += smv * o2b[l2*DDIM + tid + 256];
    }
    float diff = fabsf(mpb[tid] - np0) + fabsf(mpb[tid+256] - np1);
    red[tid] = diff;
    __syncthreads();
    for (int s = 128; s > 0; s >>= 1) {
        if (tid < s) red[tid] += red[tid + s];
        __syncthreads();
    }
    if (tid == 0) sim[b] = expf(-red[0]);
}

// ---------------------------------------------------------------------------
// commonWords + masked maxes (unchanged)
// ---------------------------------------------------------------------------
__global__ __launch_bounds__(256) void k_common(
    const int*   __restrict__ t1, const int* __restrict__ t2,
    const float* __restrict__ o1, const float* __restrict__ o2,
    float* __restrict__ e1h, float* __restrict__ e2h)
{
    const int b   = blockIdx.x;
    const int tid = threadIdx.x;
    __shared__ int ss1[64];
    __shared__ int smask[64];
    __shared__ int spos[64];
    __shared__ int sany;
    if (tid == 0) sany = 0;
    if (tid < 64) ss1[tid] = t1[tid*NB + b];
    __syncthreads();
    if (tid < 64) {
        int s2 = t2[tid*NB + b];
        int dmax = -1;
        for (int j = 0; j < 64; ++j)
            if (ss1[j] == s2) dmax = j;
        int mk = (dmax > 1) && (s2 > 0);
        smask[tid] = mk;
        spos[tid]  = dmax < 0 ? 0 : dmax;
        if (mk) sany = 1;
    }
    __syncthreads();
    int has = sany;
#pragma unroll
    for (int half = 0; half < 2; ++half) {
        int dd = tid + half*256;
        float m1 = -3.402823466e+38f, m2 = -3.402823466e+38f;
        for (int i = 0; i < 64; ++i) {
            if (smask[i]) {
                m1 = fmaxf(m1, o1[(size_t)spos[i]*(NB*DDIM) + b*DDIM + dd]);
                m2 = fmaxf(m2, o2[(size_t)i      *(NB*DDIM) + b*DDIM + dd]);
            }
        }
        e1h[b*DDIM + dd] = has ? m1 : 0.0f;
        e2h[b*DDIM + dd] = has ? m2 : 0.0f;
    }
}

// ---------------------------------------------------------------------------
extern "C" void kernel_launch(void* const* d_in, const int* in_sizes, int n_in,
                              void* d_out, int out_size, void* d_ws, size_t ws_size,
                              hipStream_t stream)
{
    (void)in_sizes; (void)n_in; (void)out_size; (void)ws_size;
    const int*   t1    = (const int*)d_in[0];
    const int*   t2    = (const int*)d_in[1];
    const float* emb   = (const float*)d_in[2];
    const float* wih_f = (const float*)d_in[3];
    const float* whh_f = (const float*)d_in[4];
    const float* bih_f = (const float*)d_in[5];
    const float* bhh_f = (const float*)d_in[6];
    const float* wih_b = (const float*)d_in[7];
    const float* whh_b = (const float*)d_in[8];
    const float* bih_b = (const float*)d_in[9];
    const float* bhh_b = (const float*)d_in[10];
    float* out = (float*)d_out;

    char* ws = (char*)d_ws;
    size_t off = 0;
    auto carve = [&](size_t bytes) -> void* {
        void* p = ws + off;
        off = (off + bytes + 255) & ~(size_t)255;
        return p;
    };
    float*  o1    = (float*)carve(sizeof(float)*(size_t)L_SEQ*NB*DDIM);
    float*  o2    = (float*)carve(sizeof(float)*(size_t)L_SEQ*NB*DDIM);
    bf16_t* whhB  = (bf16_t*)carve(sizeof(bf16_t)*2*1024*HID);
    bf16_t* Bw    = (bf16_t*)carve(sizeof(bf16_t)*(size_t)NCOL*EMBD);
    float*  bias  = (float*)carve(sizeof(float)*NCOL);
    float*  mp1   = (float*)carve(sizeof(float)*NB*DDIM);
    bf16_t* xgT   = (bf16_t*)carve(sizeof(bf16_t)*(size_t)MTOT*NCOL);  // 67 MB
    bf16_t* A     = (bf16_t*)o1;   // A dead before scan writes o1

    hipFuncSetAttribute((const void*)lstm_scan6,
                        hipFuncAttributeMaxDynamicSharedMemorySize, 147456);

    hipLaunchKernelGGL(k_pack_a,    dim3(4096), dim3(256), 0, stream, t1, t2, emb, A);
    hipLaunchKernelGGL(k_pack_b,    dim3(512),  dim3(256), 0, stream, wih_f, wih_b, Bw);
    hipLaunchKernelGGL(k_pack_whh,  dim3(256),  dim3(256), 0, stream, whh_f, whh_b, whhB);
    hipLaunchKernelGGL(k_pack_bias, dim3(8),    dim3(256), 0, stream,
                       bih_f, bhh_f, bih_b, bhh_b, bias);

    hipLaunchKernelGGL(xg_gemm4, dim3(16, 128), dim3(256), 0, stream, A, Bw, bias, xgT);

    hipLaunchKernelGGL(lstm_scan6, dim3(8, 4), dim3(512), 147456, stream,
                       whhB, xgT, o1, o2);

    hipLaunchKernelGGL(k_mp1,    dim3(256), dim3(256), 0, stream, o1, mp1);
    hipLaunchKernelGGL(k_att,    dim3(128), dim3(256), 0, stream, o2, mp1, out);
    hipLaunchKernelGGL(k_common, dim3(128), dim3(256), 0, stream,
                       t1, t2, o1, o2, out + NB, out + NB + NB*DDIM);
}

// Round 8
// 644.213 us; speedup vs baseline: 3.5552x; 1.0359x over previous
//
#include <hip/hip_runtime.h>
#include <hip/hip_bf16.h>
#include <math.h>

#define L_SEQ 64
#define NB    128
#define EMBD  512
#define HID   256
#define G4    1024      // 4*HID
#define NCOL  2048      // 2 dirs * 4H
#define DDIM  512       // 2*HID
#define MS    (L_SEQ*NB)   // 8192 rows per sentence
#define MTOT  (2*MS)       // 16384 combined rows

typedef __bf16 bf16_t;
typedef bf16_t bf16x4 __attribute__((ext_vector_type(4)));
typedef bf16_t bf16x8 __attribute__((ext_vector_type(8)));
typedef float  floatx4 __attribute__((ext_vector_type(4)));
typedef float  floatx8 __attribute__((ext_vector_type(8)));

__device__ __forceinline__ bf16x8 cvt_bf16x8(floatx8 v) {
    bf16x8 r;
    r[0]=(bf16_t)v[0]; r[1]=(bf16_t)v[1]; r[2]=(bf16_t)v[2]; r[3]=(bf16_t)v[3];
    r[4]=(bf16_t)v[4]; r[5]=(bf16_t)v[5]; r[6]=(bf16_t)v[6]; r[7]=(bf16_t)v[7];
    return r;
}

__device__ __forceinline__ void gload_lds16(const bf16_t* g, bf16_t* l) {
    __builtin_amdgcn_global_load_lds(
        (const __attribute__((address_space(1))) unsigned int*)(g),
        (__attribute__((address_space(3))) unsigned int*)(l), 16, 0, 0);
}

__device__ __forceinline__ float fsigmoid(float x) {
    return __builtin_amdgcn_rcpf(1.0f + __expf(-x));
}
__device__ __forceinline__ float ftanh(float x) {
    return 1.0f - 2.0f * __builtin_amdgcn_rcpf(__expf(2.0f*x) + 1.0f);
}

// Raw workgroup barrier: drain LDS ops only (h ping-pong visibility), skip the
// vmcnt(0) store-ack drain __syncthreads would force (o-stores have no
// intra-kernel consumer; kernel-end drain covers the downstream kernels).
#define LDS_BARRIER() asm volatile("s_waitcnt lgkmcnt(0)\n\ts_barrier" ::: "memory")

// ---------------------------------------------------------------------------
// Pack kernels (unchanged)
// ---------------------------------------------------------------------------
__global__ __launch_bounds__(256) void k_pack_a(const int* __restrict__ t1,
                                                const int* __restrict__ t2,
                                                const float* __restrict__ emb,
                                                bf16_t* __restrict__ A)
{
    int gid = blockIdx.x*256 + threadIdx.x;
    int row = gid >> 6;
    int k8  = (gid & 63) * 8;
    int tok = (row < MS) ? t1[row] : t2[row - MS];
    floatx8 v = *(const floatx8*)(emb + (size_t)tok*EMBD + k8);
    *(bf16x8*)(A + (size_t)row*EMBD + k8) = cvt_bf16x8(v);
}

__global__ __launch_bounds__(256) void k_pack_b(const float* __restrict__ wih_f,
                                                const float* __restrict__ wih_b,
                                                bf16_t* __restrict__ B)
{
    int gid = blockIdx.x*256 + threadIdx.x;
    int n   = gid >> 6;
    int k8  = (gid & 63) * 8;
    const float* src = (n >= 1024) ? (wih_b + (size_t)(n-1024)*EMBD)
                                   : (wih_f + (size_t)n*EMBD);
    *(bf16x8*)(B + (size_t)n*EMBD + k8) = cvt_bf16x8(*(const floatx8*)(src + k8));
}

__global__ __launch_bounds__(256) void k_pack_whh(const float* __restrict__ whh_f,
                                                  const float* __restrict__ whh_b,
                                                  bf16_t* __restrict__ whhB)
{
    int gid = blockIdx.x*256 + threadIdx.x;
    int r2  = gid >> 5;
    int k8  = (gid & 31) * 8;
    const float* src = (r2 >= 1024) ? (whh_b + (size_t)(r2-1024)*HID)
                                    : (whh_f + (size_t)r2*HID);
    *(bf16x8*)(whhB + (size_t)r2*HID + k8) = cvt_bf16x8(*(const floatx8*)(src + k8));
}

__global__ __launch_bounds__(256) void k_pack_bias(const float* __restrict__ bih_f,
                                                   const float* __restrict__ bhh_f,
                                                   const float* __restrict__ bih_b,
                                                   const float* __restrict__ bhh_b,
                                                   float* __restrict__ bias)
{
    int n = blockIdx.x*256 + threadIdx.x;
    bias[n] = (n >= 1024) ? (bih_b[n-1024] + bhh_b[n-1024])
                          : (bih_f[n] + bhh_f[n]);
}

// ---------------------------------------------------------------------------
// xg GEMM v4 (unchanged): epilogue stores bf16 per-chunk layout
//   xgT[(((s2*8 + ch)*64 + l)*1024 + gcol)*16 + bi],  ch=b>>4, bi=b&15
// ---------------------------------------------------------------------------
__global__ __launch_bounds__(256) void xg_gemm4(const bf16_t* __restrict__ A,
                                                const bf16_t* __restrict__ B,
                                                const float* __restrict__ bias,
                                                bf16_t* __restrict__ xgT)
{
    __shared__ bf16_t As[128*32];
    __shared__ bf16_t Bs[128*32];
    const int tid  = threadIdx.x;
    const int wid  = tid >> 6;
    const int lane = tid & 63;
    const int l15  = lane & 15;
    const int quad = lane >> 4;
    const int m0   = blockIdx.y * 128;
    const int n0   = blockIdx.x * 128;
    const int mw   = (wid & 1) * 64;
    const int nw   = (wid >> 1) * 64;

    float biasv[4];
#pragma unroll
    for (int ni = 0; ni < 4; ++ni) biasv[ni] = bias[n0 + nw + ni*16 + l15];

    const int srow = tid >> 2;
    const int sk8  = (tid & 3) * 8;

    floatx4 acc[4][4] = {};
    for (int kk = 0; kk < EMBD; kk += 32) {
#pragma unroll
        for (int inst = 0; inst < 2; ++inst) {
            gload_lds16(A + (size_t)(m0 + inst*64 + srow)*EMBD + kk + sk8,
                        As + inst*2048 + wid*512);
            gload_lds16(B + (size_t)(n0 + inst*64 + srow)*EMBD + kk + sk8,
                        Bs + inst*2048 + wid*512);
        }
        __syncthreads();
        bf16x8 a[4], b[4];
#pragma unroll
        for (int mi = 0; mi < 4; ++mi)
            a[mi] = *(const bf16x8*)(As + (mw + mi*16 + l15)*32 + quad*8);
#pragma unroll
        for (int ni = 0; ni < 4; ++ni)
            b[ni] = *(const bf16x8*)(Bs + (nw + ni*16 + l15)*32 + quad*8);
#pragma unroll
        for (int mi = 0; mi < 4; ++mi)
#pragma unroll
            for (int ni = 0; ni < 4; ++ni)
                acc[mi][ni] = __builtin_amdgcn_mfma_f32_16x16x32_bf16(
                                  a[mi], b[ni], acc[mi][ni], 0, 0, 0);
        __syncthreads();
    }

    // epilogue: per-chunk transposed bf16 store
    const int sent = blockIdx.y >> 6;       // m = sent*8192 + l*128 + b
    const int l    = blockIdx.y & 63;
    const int dir  = n0 >> 10;              // uniform per block
    const int s2   = sent*2 + dir;
#pragma unroll
    for (int mi = 0; mi < 4; ++mi)
#pragma unroll
        for (int ni = 0; ni < 4; ++ni) {
            int gcol = (n0 & 1023) + nw + ni*16 + l15;
            int b    = mw + mi*16 + quad*4;
            int ch   = b >> 4;
            int bi   = b & 15;
            bf16x4 v;
#pragma unroll
            for (int r = 0; r < 4; ++r) v[r] = (bf16_t)(acc[mi][ni][r] + biasv[ni]);
            *(bf16x4*)(xgT + ((size_t)((s2*8 + ch)*64 + l)*1024 + gcol)*16 + bi) = v;
        }
}

// ---------------------------------------------------------------------------
// LSTM scan v7 = v6b + latency fixes:
//  * amdgpu_waves_per_eu(2,2): per-EU VGPR file is 512 regs; at 2 waves/EU the
//    allocator may use 256/wave (R7 showed it targeted 4 waves -> 128 -> AGPR
//    shuffle/spill of the 128-reg weight file).
//  * both streamed batches (ks6+ks7) issued at step top -> L2 latency hides
//    under the ks0..5 MFMA phase.
//  * xg registers double-buffered across steps.
//  * raw lgkm-only barrier (no per-step vmcnt store-ack drain).
// ---------------------------------------------------------------------------
__global__
__attribute__((amdgpu_flat_work_group_size(512, 512), amdgpu_waves_per_eu(2, 2)))
void lstm_scan7(
    const bf16_t* __restrict__ whhB,   // [2][1024][256] bf16
    const bf16_t* __restrict__ xgT,    // per-chunk layout
    float* __restrict__ o1, float* __restrict__ o2)
{
    extern __shared__ char smem[];
    bf16_t* hb = (bf16_t*)smem;              // 2 frames x 4096 bf16 = 16 KB
    bf16_t* BL = (bf16_t*)(smem + 16384);    // 128 frags x 512 bf16 = 128 KB

    const int tid  = threadIdx.x;
    const int wv   = tid >> 6;            // 0..7
    const int lane = tid & 63;
    const int l15  = lane & 15;
    const int quad = lane >> 4;
    const int s2   = blockIdx.y;          // sent*2 + dr
    const int sent = s2 >> 1;
    const int dr   = s2 & 1;
    const int chunk= blockIdx.x;
    const int b0   = chunk * 16;
    float* o = sent ? o2 : o1;
    const bf16_t* bb = whhB + (size_t)dr * (1024*HID);

    // ---- LDS weight preload: ks 4,5 for all 8 nt (nt = gate*2 + unit-half)
#pragma unroll
    for (int nt = 0; nt < 8; ++nt) {
        const int g = nt >> 1, u = nt & 1;
        const int col = g*256 + wv*32 + u*16 + l15;
#pragma unroll
        for (int ksl = 0; ksl < 2; ++ksl)
            gload_lds16(bb + (size_t)col*HID + (4+ksl)*32 + quad*8,
                        BL + (size_t)(wv*16 + nt*2 + ksl)*512);
    }

    // ---- VGPR weights ks0..3 — volatile loads: no rematerialization
    bf16x8 bwc[8][4];
#pragma unroll
    for (int nt = 0; nt < 8; ++nt) {
        const int g = nt >> 1, u = nt & 1;
        const bf16_t* cp = bb + (size_t)(g*256 + wv*32 + u*16 + l15)*HID + quad*8;
#pragma unroll
        for (int ks = 0; ks < 4; ++ks)
            bwc[nt][ks] = *(const volatile bf16x8*)(cp + ks*32);
    }

    // zero h frame 0
    for (int i = tid; i < 4096; i += 512) hb[i] = (bf16_t)0.0f;
    __syncthreads();   // full drain once (also covers global_load_lds)

    float cst[2][4] = {};
    int pp = 0;

    // xg double-buffer: preload step 0
    bf16x4 xvc[8], xvn[8];
    {
        const int lt0 = dr ? (L_SEQ-1) : 0;
        const bf16_t* xp = xgT + (size_t)((s2*8 + chunk)*64 + lt0)*16384;
#pragma unroll
        for (int nt = 0; nt < 8; ++nt) {
            const int g = nt >> 1, u = nt & 1;
            xvc[nt] = *(const bf16x4*)(xp + (size_t)(g*256 + wv*32 + u*16 + l15)*16
                                       + quad*4);
        }
    }

    for (int t = 0; t < L_SEQ; ++t) {
        const int lt = dr ? (L_SEQ-1-t) : t;
        asm volatile("" ::: "memory");   // keep in-loop loads in-loop

        // prefetch next step's xg (t=63: reload t=63, harmless)
        {
            const int tn  = (t < L_SEQ-1) ? t+1 : t;
            const int ltn = dr ? (L_SEQ-1-tn) : tn;
            const bf16_t* xp = xgT + (size_t)((s2*8 + chunk)*64 + ltn)*16384;
#pragma unroll
            for (int nt = 0; nt < 8; ++nt) {
                const int g = nt >> 1, u = nt & 1;
                xvn[nt] = *(const bf16x4*)(xp + (size_t)(g*256 + wv*32 + u*16 + l15)*16
                                           + quad*4);
            }
        }

        floatx4 acc[8] = {};
        if (t > 0) {
            // both streamed batches issued up front: latency hides under ks0..5
            bf16x8 sb6[8], sb7[8];
#pragma unroll
            for (int nt = 0; nt < 8; ++nt) {
                const int g = nt >> 1, u = nt & 1;
                const bf16_t* cp = bb + (size_t)(g*256 + wv*32 + u*16 + l15)*HID;
                sb6[nt] = *(const bf16x8*)(cp + 6*32 + quad*8);
                sb7[nt] = *(const bf16x8*)(cp + 7*32 + quad*8);
            }

            const bf16_t* fr = hb + pp*4096;
            // ks0..3: VGPR weights
#pragma unroll
            for (int ks = 0; ks < 4; ++ks) {
                bf16x8 af = *(const bf16x8*)(fr + ((ks*4 + quad)*16 + l15)*8);
#pragma unroll
                for (int nt = 0; nt < 8; ++nt)
                    acc[nt] = __builtin_amdgcn_mfma_f32_16x16x32_bf16(
                                  af, bwc[nt][ks], acc[nt], 0, 0, 0);
            }
            // ks4,5: LDS weights
#pragma unroll
            for (int ksl = 0; ksl < 2; ++ksl) {
                bf16x8 af = *(const bf16x8*)(fr + (((4+ksl)*4 + quad)*16 + l15)*8);
#pragma unroll
                for (int nt = 0; nt < 8; ++nt) {
                    bf16x8 bl = *(const bf16x8*)(BL + (size_t)(wv*16 + nt*2 + ksl)*512
                                                 + lane*8);
                    acc[nt] = __builtin_amdgcn_mfma_f32_16x16x32_bf16(
                                  af, bl, acc[nt], 0, 0, 0);
                }
            }
            // ks6, ks7: streamed weights
            {
                bf16x8 af6 = *(const bf16x8*)(fr + ((6*4 + quad)*16 + l15)*8);
#pragma unroll
                for (int nt = 0; nt < 8; ++nt)
                    acc[nt] = __builtin_amdgcn_mfma_f32_16x16x32_bf16(
                                  af6, sb6[nt], acc[nt], 0, 0, 0);
                bf16x8 af7 = *(const bf16x8*)(fr + ((7*4 + quad)*16 + l15)*8);
#pragma unroll
                for (int nt = 0; nt < 8; ++nt)
                    acc[nt] = __builtin_amdgcn_mfma_f32_16x16x32_bf16(
                                  af7, sb7[nt], acc[nt], 0, 0, 0);
            }
        }

        // epilogue: rows m = quad*4+r, units j = wv*32 + u*16 + l15
        bf16_t* fw = hb + (pp^1)*4096;
#pragma unroll
        for (int u = 0; u < 2; ++u) {
            const int j = wv*32 + u*16 + l15;
            float* orow = o + (size_t)(lt*NB + b0)*DDIM + dr*HID + j;
#pragma unroll
            for (int r = 0; r < 4; ++r) {
                const int m = quad*4 + r;
                float gi = acc[0*2+u][r] + (float)xvc[0*2+u][r];
                float gf = acc[1*2+u][r] + (float)xvc[1*2+u][r];
                float gg = acc[2*2+u][r] + (float)xvc[2*2+u][r];
                float go = acc[3*2+u][r] + (float)xvc[3*2+u][r];
                float cv = fsigmoid(gf)*cst[u][r] + fsigmoid(gi)*ftanh(gg);
                cst[u][r] = cv;
                float hv = fsigmoid(go)*ftanh(cv);
                orow[(size_t)m*DDIM] = hv;
                fw[((j >> 3)*16 + m)*8 + (j & 7)] = (bf16_t)hv;
            }
        }
#pragma unroll
        for (int nt = 0; nt < 8; ++nt) xvc[nt] = xvn[nt];
        LDS_BARRIER();
        pp ^= 1;
    }
}

// ---------------------------------------------------------------------------
// mp1[b,d] = max_l o1[l,b,d]
// ---------------------------------------------------------------------------
__global__ __launch_bounds__(256) void k_mp1(const float* __restrict__ o1,
                                             float* __restrict__ mp1)
{
    int gid = blockIdx.x*256 + threadIdx.x;
    float m = -3.402823466e+38f;
    for (int l = 0; l < L_SEQ; ++l)
        m = fmaxf(m, o1[(size_t)l*(NB*DDIM) + gid]);
    mp1[gid] = m;
}

// ---------------------------------------------------------------------------
// attention + sim (unchanged)
// ---------------------------------------------------------------------------
__global__ __launch_bounds__(256) void k_att(const float* __restrict__ o2,
                                             const float* __restrict__ mp1,
                                             float* __restrict__ sim)
{
    const int b   = blockIdx.x;
    const int tid = threadIdx.x;
    const int l   = tid & 63;
    const int cp  = tid >> 6;
    __shared__ float spart[256];
    __shared__ float satt[64], sexp[64], ssm[64];
    __shared__ float red[256];

    const float* o2b = o2  + (size_t)b*32768;
    const float* mpb = mp1 + b*DDIM;

    float p = 0.0f;
    for (int d = cp*128; d < cp*128 + 128; ++d)
        p += mpb[d] * o2b[d*64 + l];
    spart[tid] = p;
    __syncthreads();
    if (tid < 64)
        satt[tid] = spart[tid] + spart[tid+64] + spart[tid+128] + spart[tid+192];
    __syncthreads();
    if (tid < 64) {
        float mx = satt[0];
        for (int i = 1; i < 64; ++i) mx = fmaxf(mx, satt[i]);
        sexp[tid] = expf(satt[tid] - mx);
    }
    __syncthreads();
    if (tid < 64) {
        float s = 0.0f;
        for (int i = 0; i < 64; ++i) s += sexp[i];
        ssm[tid] = sexp[tid] / s;
    }
    __syncthreads();

    float np0 = 0.0f, np1 = 0.0f;
    for (int l2 = 0; l2 < 64; ++l2) {
        float smv = ssm[l2];
        np0 += smv * o2b[l2*DDIM + tid];
        np1 += smv * o2b[l2*DDIM + tid + 256];
    }
    float diff = fabsf(mpb[tid] - np0) + fabsf(mpb[tid+256] - np1);
    red[tid] = diff;
    __syncthreads();
    for (int s = 128; s > 0; s >>= 1) {
        if (tid < s) red[tid] += red[tid + s];
        __syncthreads();
    }
    if (tid == 0) sim[b] = expf(-red[0]);
}

// ---------------------------------------------------------------------------
// commonWords + masked maxes (unchanged)
// ---------------------------------------------------------------------------
__global__ __launch_bounds__(256) void k_common(
    const int*   __restrict__ t1, const int* __restrict__ t2,
    const float* __restrict__ o1, const float* __restrict__ o2,
    float* __restrict__ e1h, float* __restrict__ e2h)
{
    const int b   = blockIdx.x;
    const int tid = threadIdx.x;
    __shared__ int ss1[64];
    __shared__ int smask[64];
    __shared__ int spos[64];
    __shared__ int sany;
    if (tid == 0) sany = 0;
    if (tid < 64) ss1[tid] = t1[tid*NB + b];
    __syncthreads();
    if (tid < 64) {
        int s2 = t2[tid*NB + b];
        int dmax = -1;
        for (int j = 0; j < 64; ++j)
            if (ss1[j] == s2) dmax = j;
        int mk = (dmax > 1) && (s2 > 0);
        smask[tid] = mk;
        spos[tid]  = dmax < 0 ? 0 : dmax;
        if (mk) sany = 1;
    }
    __syncthreads();
    int has = sany;
#pragma unroll
    for (int half = 0; half < 2; ++half) {
        int dd = tid + half*256;
        float m1 = -3.402823466e+38f, m2 = -3.402823466e+38f;
        for (int i = 0; i < 64; ++i) {
            if (smask[i]) {
                m1 = fmaxf(m1, o1[(size_t)spos[i]*(NB*DDIM) + b*DDIM + dd]);
                m2 = fmaxf(m2, o2[(size_t)i      *(NB*DDIM) + b*DDIM + dd]);
            }
        }
        e1h[b*DDIM + dd] = has ? m1 : 0.0f;
        e2h[b*DDIM + dd] = has ? m2 : 0.0f;
    }
}

// ---------------------------------------------------------------------------
extern "C" void kernel_launch(void* const* d_in, const int* in_sizes, int n_in,
                              void* d_out, int out_size, void* d_ws, size_t ws_size,
                              hipStream_t stream)
{
    (void)in_sizes; (void)n_in; (void)out_size; (void)ws_size;
    const int*   t1    = (const int*)d_in[0];
    const int*   t2    = (const int*)d_in[1];
    const float* emb   = (const float*)d_in[2];
    const float* wih_f = (const float*)d_in[3];
    const float* whh_f = (const float*)d_in[4];
    const float* bih_f = (const float*)d_in[5];
    const float* bhh_f = (const float*)d_in[6];
    const float* wih_b = (const float*)d_in[7];
    const float* whh_b = (const float*)d_in[8];
    const float* bih_b = (const float*)d_in[9];
    const float* bhh_b = (const float*)d_in[10];
    float* out = (float*)d_out;

    char* ws = (char*)d_ws;
    size_t off = 0;
    auto carve = [&](size_t bytes) -> void* {
        void* p = ws + off;
        off = (off + bytes + 255) & ~(size_t)255;
        return p;
    };
    float*  o1    = (float*)carve(sizeof(float)*(size_t)L_SEQ*NB*DDIM);
    float*  o2    = (float*)carve(sizeof(float)*(size_t)L_SEQ*NB*DDIM);
    bf16_t* whhB  = (bf16_t*)carve(sizeof(bf16_t)*2*1024*HID);
    bf16_t* Bw    = (bf16_t*)carve(sizeof(bf16_t)*(size_t)NCOL*EMBD);
    float*  bias  = (float*)carve(sizeof(float)*NCOL);
    float*  mp1   = (float*)carve(sizeof(float)*NB*DDIM);
    bf16_t* xgT   = (bf16_t*)carve(sizeof(bf16_t)*(size_t)MTOT*NCOL);  // 67 MB
    bf16_t* A     = (bf16_t*)o1;   // A dead before scan writes o1

    hipFuncSetAttribute((const void*)lstm_scan7,
                        hipFuncAttributeMaxDynamicSharedMemorySize, 147456);

    hipLaunchKernelGGL(k_pack_a,    dim3(4096), dim3(256), 0, stream, t1, t2, emb, A);
    hipLaunchKernelGGL(k_pack_b,    dim3(512),  dim3(256), 0, stream, wih_f, wih_b, Bw);
    hipLaunchKernelGGL(k_pack_whh,  dim3(256),  dim3(256), 0, stream, whh_f, whh_b, whhB);
    hipLaunchKernelGGL(k_pack_bias, dim3(8),    dim3(256), 0, stream,
                       bih_f, bhh_f, bih_b, bhh_b, bias);

    hipLaunchKernelGGL(xg_gemm4, dim3(16, 128), dim3(256), 0, stream, A, Bw, bias, xgT);

    hipLaunchKernelGGL(lstm_scan7, dim3(8, 4), dim3(512), 147456, stream,
                       whhB, xgT, o1, o2);

    hipLaunchKernelGGL(k_mp1,    dim3(256), dim3(256), 0, stream, o1, mp1);
    hipLaunchKernelGGL(k_att,    dim3(128), dim3(256), 0, stream, o2, mp1, out);
    hipLaunchKernelGGL(k_common, dim3(128), dim3(256), 0, stream,
                       t1, t2, o1, o2, out + NB, out + NB + NB*DDIM);
}